// Round 12
// baseline (434.183 us; speedup 1.0000x reference)
//
#include <hip/hip_runtime.h>
#include <hip/hip_bf16.h>

// QLSTM: T=512, B=256, D_IN=128, D_H=128.
// Gates are per-batch SCALARS broadcast over hidden dim => h,c uniform across
// hidden dim. comb@W[0] = x@W[0][:128] + h*sum(W[0][128:]).
// R12: FULL FUSION. 32 blocks x 256 threads. Per 64-step chunk (double-buffered):
//   wave 0     : R11's serial scan chain (4 lanes/batch, DPP gate exchange),
//                LDS zb[k&1] -> LDS hb[k&1]
//   waves 1-3  : GEMV chunk k+1 (x -> zb[(k+1)&1], xz math unchanged) and
//                broadcast-write chunk k-1 (hb[(k-1)&1] -> d_out).
// The 67MB x read and 67MB out write hide under the scan's serial chain;
// xz/hscan intermediates and 2 kernel launches eliminated.

constexpr int T = 512;
constexpr int Bsz = 256;
constexpr int R = T * Bsz;          // 131072 output rows (main)
constexpr int BPB = 8;              // batches per block
constexpr int CH = 64;              // timesteps per chunk
constexpr int NCH = T / CH;         // 8
constexpr float INV2PI = 0.15915494309189535f;

// tanh(c), |c|<=2.07 (provable bound): odd deg-9 polynomial (no rcp),
// err ~1e-3 typ, <=5e-3 near endpoint.
__device__ __forceinline__ float tanh9(float c) {
    const float y  = c * c;
    const float y2 = y * y;
    const float lo  = fmaf(y, -0.321470f, 0.999168f);
    const float hi  = fmaf(y, 0.0016407f, -0.0199491f);
    const float mid = fmaf(y, hi, 0.101498f);
    return c * fmaf(y2, mid, lo);
}

template<int CTRL>
__device__ __forceinline__ float dppq(float x) {
    return __builtin_bit_cast(float,
        __builtin_amdgcn_mov_dpp(__builtin_bit_cast(int, x), CTRL, 0xF, 0xF, true));
}

__device__ __forceinline__ float wsum(const float* __restrict__ W, int lane) {
    float s = W[128 + lane] + W[192 + lane];
#pragma unroll
    for (int off = 32; off; off >>= 1) s += __shfl_xor(s, off, 64);
    return s;  // butterfly: all lanes hold the sum
}

__global__ __launch_bounds__(256, 1) void fused_kernel(
    const float* __restrict__ x,
    const float* __restrict__ Wf, const float* __restrict__ bf, const float* __restrict__ tf,
    const float* __restrict__ Wi, const float* __restrict__ bi, const float* __restrict__ ti,
    const float* __restrict__ Wu, const float* __restrict__ bu, const float* __restrict__ tu,
    const float* __restrict__ Wo, const float* __restrict__ bo, const float* __restrict__ to_,
    float4* __restrict__ out4)
{
    __shared__ __align__(16) float zb[2][CH * 32];   // [buf][t_local*32 + bg*4 + q]
    __shared__ __align__(16) float hb[2][CH * 32];   // [buf][t_local*32 + lane] (quad-replicated)
    __shared__ float c_lds[32];

    const int tid  = threadIdx.x;
    const int bb   = blockIdx.x * BPB;
    const int wv   = tid >> 6;           // wave id 0..3
    const int lane = tid & 63;
    const int hl   = lane & 31;          // half-wave lane
    const int half = lane >> 5;

    // ---- scan-wave setup (wave 0) ----
    float h = 0.0f, c = 0.0f, sw = 0.0f;
    float K0 = 0, K1 = 0, K3 = 0, K5 = 0, K7 = 0;
    // ---- producer setup (waves 1-3) ----
    float4 wfv{}, wiv{}, wuv{}, wov{};
    float cf = 0, ci = 0, cu = 0, co = 0;

    // producer GEMV for chunk kk into zb[buf] (xz_kernel math, half-wave/row)
    auto produce = [&](int kk, int buf) {
        for (int p = wv - 1; p < (CH * BPB) / 2; p += 3) {   // 256 row-pairs / 3 waves
            const int rowi = 2 * p + half;                   // t_local*8 + bg
            const int tl = rowi >> 3, bg = rowi & 7;
            const int t  = kk * CH + tl;
            const float4 xv = *(const float4*)(x + ((size_t)t * Bsz + bb + bg) * 128 + hl * 4);
            float pf = xv.x * wfv.x + xv.y * wfv.y + xv.z * wfv.z + xv.w * wfv.w;
            float pi = xv.x * wiv.x + xv.y * wiv.y + xv.z * wiv.z + xv.w * wiv.w;
            float pu = xv.x * wuv.x + xv.y * wuv.y + xv.z * wuv.z + xv.w * wuv.w;
            float po = xv.x * wov.x + xv.y * wov.y + xv.z * wov.z + xv.w * wov.w;
#pragma unroll
            for (int off = 16; off; off >>= 1) {
                pf += __shfl_xor(pf, off, 64);
                pi += __shfl_xor(pi, off, 64);
                pu += __shfl_xor(pu, off, 64);
                po += __shfl_xor(po, off, 64);
            }
            if (hl == 0) {
                *(float4*)&zb[buf][tl * 32 + bg * 4] =
                    make_float4((pf + cf) * INV2PI, (pi + ci) * INV2PI,
                                (pu + cu) * INV2PI, (po + co) * INV2PI);
            }
        }
    };

    // broadcast-write chunk kk's h rows to d_out (value splat across 128 cols)
    auto flush = [&](int kk, int buf, int base, int stride) {
        for (int j = base; j < CH * BPB * 32; j += stride) {   // 16384 float4
            const int row = j >> 5, col = j & 31;
            const int tl = row >> 3, bg = row & 7;
            const float v = hb[buf][tl * 32 + bg * 4];
            out4[((size_t)(kk * CH + tl) * Bsz + bb + bg) * 32 + col] =
                make_float4(v, v, v, v);
        }
    };

    if (wv == 0) {
        const float swf = wsum(Wf, lane) * INV2PI;
        const float swi = wsum(Wi, lane) * INV2PI;
        const float swu = wsum(Wu, lane) * INV2PI;
        const float swo = wsum(Wo, lane) * INV2PI;
        const int q = tid & 3;           // gate: 0=f 1=i 2=g(tanh) 3=o
        sw = (q == 0) ? swf : (q == 1) ? swi : (q == 2) ? swu : swo;
        const bool tq = (q == 2);
        K0 = tq ? 0.0f        : 0.5f;
        K1 = tq ? 0.999904f   : 0.249976f;
        K3 = tq ? -0.331066f  : -0.0206916f;
        K5 = tq ? 0.120476f   : 0.00188244f;
        K7 = tq ? -0.0277200f : -0.000108281f;
    } else {
        wfv = ((const float4*)Wf)[hl];
        wiv = ((const float4*)Wi)[hl];
        wuv = ((const float4*)Wu)[hl];
        wov = ((const float4*)Wo)[hl];
        cf = bf[0] + tf[0];
        ci = bi[0] + ti[0];
        cu = bu[0] + tu[0];
        co = bo[0] + to_[0];
        produce(0, 0);                   // prologue: fill chunk 0
    }

#define QSTEP(Z)                                                  \
    {                                                             \
        const float u  = fmaf(h, sw, (Z));                        \
        const float v  = __builtin_amdgcn_cosf(u);                \
        const float v2 = v * v;                                   \
        const float v4 = v2 * v2;                                 \
        const float ph = fmaf(v2, K7, K5);                        \
        const float pl = fmaf(v2, K3, K1);                        \
        const float gown = fmaf(v, fmaf(v4, ph, pl), K0);         \
        const float f = dppq<0x00>(gown);                         \
        const float i = dppq<0x55>(gown);                         \
        const float g = dppq<0xAA>(gown);                         \
        const float o = dppq<0xFF>(gown);                         \
        c = fmaf(f, c, i * g);                                    \
        h = o * tanh9(c);                                         \
        *hw = h;                                                  \
        hw += 32;                                                 \
    }

    for (int k = 0; k < NCH; ++k) {
        __syncthreads();                 // zb[k&1] ready; hb[(k-1)&1] ready
        if (wv == 0) {
            if (tid < 32) {
                const float* zp = zb[k & 1] + tid;
                float* hw = hb[k & 1] + tid;
                for (int s = 0; s < CH; s += 8) {
                    const float* zt = zp + s * 32;
                    const float y0 = zt[0 * 32];
                    const float y1 = zt[1 * 32];
                    const float y2 = zt[2 * 32];
                    const float y3 = zt[3 * 32];
                    const float y4 = zt[4 * 32];
                    const float y5 = zt[5 * 32];
                    const float y6 = zt[6 * 32];
                    const float y7 = zt[7 * 32];
                    QSTEP(y0); QSTEP(y1); QSTEP(y2); QSTEP(y3);
                    QSTEP(y4); QSTEP(y5); QSTEP(y6); QSTEP(y7);
                }
                if (k == NCH - 1) c_lds[tid] = c;
            }
        } else {
            if (k + 1 < NCH) produce(k + 1, (k + 1) & 1);
            if (k >= 1)      flush(k - 1, (k - 1) & 1, tid - 64, 192);
        }
    }
#undef QSTEP

    __syncthreads();
    // epilogue (all 256 threads): flush chunk 7 + hx/cx tails
    flush(NCH - 1, (NCH - 1) & 1, tid, 256);
    for (int j = tid; j < 2 * BPB * 32; j += 256) {   // 512 float4
        const int kind = j >> 8;          // 0 = hx, 1 = cx
        const int r = j & 255;
        const int bg = r >> 5, col = r & 31;
        const float v = kind ? c_lds[bg * 4]
                             : hb[(NCH - 1) & 1][(CH - 1) * 32 + bg * 4];
        const size_t row = (size_t)R + (size_t)kind * Bsz + bb + bg;
        out4[row * 32 + col] = make_float4(v, v, v, v);
    }
}

extern "C" void kernel_launch(void* const* d_in, const int* in_sizes, int n_in,
                              void* d_out, int out_size, void* d_ws, size_t ws_size,
                              hipStream_t stream)
{
    const float* x  = (const float*)d_in[0];
    const float* Wf = (const float*)d_in[1];
    const float* bf = (const float*)d_in[2];
    const float* tf = (const float*)d_in[3];
    const float* Wi = (const float*)d_in[4];
    const float* bi = (const float*)d_in[5];
    const float* ti = (const float*)d_in[6];
    const float* Wu = (const float*)d_in[7];
    const float* bu = (const float*)d_in[8];
    const float* tu = (const float*)d_in[9];
    const float* Wo = (const float*)d_in[10];
    const float* bo = (const float*)d_in[11];
    const float* to_ = (const float*)d_in[12];

    fused_kernel<<<Bsz / BPB, 256, 0, stream>>>(
        x, Wf, bf, tf, Wi, bi, ti, Wu, bu, tu, Wo, bo, to_, (float4*)d_out);
}

// Round 13
// 93.529 us; speedup vs baseline: 4.6422x; 4.6422x over previous
//
#include <hip/hip_runtime.h>
#include <hip/hip_bf16.h>

// QLSTM: T=512, B=256, D_IN=128, D_H=128.
// Gates are per-batch SCALARS broadcast over hidden dim => h,c uniform across
// hidden dim. comb@W[0] = x@W[0][:128] + h*sum(W[0][128:]).
// R12 post-mortem: fusion starved HBM (32 CUs for 134MB) -> revert 3-kernel.
// R13: scan with TWO independent batch chains per lane (quad handles batches
// 2j,2j+1): chain latencies overlap each other; wall/step -> max(2x issue, chain).

constexpr int T = 512;
constexpr int Bsz = 256;
constexpr int R = T * Bsz;          // 131072 rows
constexpr float INV2PI = 0.15915494309189535f;

// ---------------- Kernel 1: xz[row] = float4(zf,zi,zu,zo)/(2pi), row = t*B+b
__global__ __launch_bounds__(256) void xz_kernel(
    const float* __restrict__ x,
    const float* __restrict__ Wf, const float* __restrict__ bf, const float* __restrict__ tf,
    const float* __restrict__ Wi, const float* __restrict__ bi, const float* __restrict__ ti,
    const float* __restrict__ Wu, const float* __restrict__ bu, const float* __restrict__ tu,
    const float* __restrict__ Wo, const float* __restrict__ bo, const float* __restrict__ to_,
    float4* __restrict__ xz)
{
    const int wglobal = blockIdx.x * 4 + (threadIdx.x >> 6);   // 0..8191
    const int lane = threadIdx.x & 63;
    const int hl = lane & 31;            // lane within half-wave
    const int half = lane >> 5;          // which row of the pair

    const float4 wfv = ((const float4*)Wf)[hl];
    const float4 wiv = ((const float4*)Wi)[hl];
    const float4 wuv = ((const float4*)Wu)[hl];
    const float4 wov = ((const float4*)Wo)[hl];

    const float cf = bf[0] + tf[0];
    const float ci = bi[0] + ti[0];
    const float cu = bu[0] + tu[0];
    const float co = bo[0] + to_[0];

    for (int it = 0; it < 8; ++it) {
        const int row = (it * 8192 + wglobal) * 2 + half;
        const float4 xv = *(const float4*)(x + (size_t)row * 128 + hl * 4);

        float pf = xv.x * wfv.x + xv.y * wfv.y + xv.z * wfv.z + xv.w * wfv.w;
        float pi = xv.x * wiv.x + xv.y * wiv.y + xv.z * wiv.z + xv.w * wiv.w;
        float pu = xv.x * wuv.x + xv.y * wuv.y + xv.z * wuv.z + xv.w * wuv.w;
        float po = xv.x * wov.x + xv.y * wov.y + xv.z * wov.z + xv.w * wov.w;

#pragma unroll
        for (int off = 16; off; off >>= 1) {
            pf += __shfl_xor(pf, off, 64);
            pi += __shfl_xor(pi, off, 64);
            pu += __shfl_xor(pu, off, 64);
            po += __shfl_xor(po, off, 64);
        }
        if (hl == 0) {
            xz[row] = make_float4((pf + cf) * INV2PI, (pi + ci) * INV2PI,
                                  (pu + cu) * INV2PI, (po + co) * INV2PI);
        }
    }
}

// ---------------- Kernel 2: scan, LDS-staged, 4 lanes/batch, 2 chains/lane.
// tanh(c), |c|<=2.07 (provable bound): odd deg-9 polynomial (no rcp),
// err ~1e-3 typ, <=5e-3 near endpoint.
__device__ __forceinline__ float tanh9(float c) {
    const float y  = c * c;
    const float y2 = y * y;
    const float lo  = fmaf(y, -0.321470f, 0.999168f);
    const float hi  = fmaf(y, 0.0016407f, -0.0199491f);
    const float mid = fmaf(y, hi, 0.101498f);
    return c * fmaf(y2, mid, lo);
}

template<int CTRL>
__device__ __forceinline__ float dppq(float x) {
    return __builtin_bit_cast(float,
        __builtin_amdgcn_mov_dpp(__builtin_bit_cast(int, x), CTRL, 0xF, 0xF, true));
}

__device__ __forceinline__ float wsum(const float* __restrict__ W, int lane) {
    float s = W[128 + lane] + W[192 + lane];
#pragma unroll
    for (int off = 32; off; off >>= 1) s += __shfl_xor(s, off, 64);
    return s;  // butterfly: all lanes hold the sum
}

constexpr int BPB = 8;                   // batches per scan block
constexpr int SCAN_BLOCKS = Bsz / BPB;   // 32

__global__ __launch_bounds__(256, 1) void scan_kernel(
    const float4* __restrict__ xz,
    const float* __restrict__ Wf, const float* __restrict__ Wi,
    const float* __restrict__ Wu, const float* __restrict__ Wo,
    float* __restrict__ hscan, float* __restrict__ cfin)
{
    __shared__ float4 lds4[T * BPB];     // 64 KB, layout [t][bg] float4=4 gates
    const int tid = threadIdx.x;
    const int bb = blockIdx.x * BPB;

    // ---- stage the entire block slice: 256 threads x 16 float4 loads
#pragma unroll
    for (int k = 0; k < T * BPB / 256; ++k) {      // 16 iterations
        const int j = k * 256 + tid;               // 0..4095
        lds4[j] = xz[(j >> 3) * Bsz + bb + (j & 7)];
    }

    // ---- per-gate hidden-weight sums (wave-wide butterfly, every wave)
    const int l = tid & 63;
    const float swf = wsum(Wf, l) * INV2PI;
    const float swi = wsum(Wi, l) * INV2PI;
    const float swu = wsum(Wu, l) * INV2PI;
    const float swo = wsum(Wo, l) * INV2PI;

    __syncthreads();
    if (tid >= BPB * 2) return;          // lanes 0..15: quad j -> batches 2j,2j+1

    const int q = tid & 3;               // gate: 0=f 1=i 2=g(tanh) 3=o
    const int j = tid >> 2;              // quad id 0..3
    const int batchA = bb + 2 * j;       // chain A / chain B = batchA+1

    // this lane's gate row-sum (already *INV2PI)
    const float sw = (q == 0) ? swf : (q == 1) ? swi : (q == 2) ? swu : swo;

    // unified odd deg-7 gate polynomial in v = cos(u):
    //   tanh lane (q==2): tanh(v); sigmoid lanes: 0.5 + 0.5*tanh(v/2) (folded).
    const bool tq = (q == 2);
    const float K0 = tq ? 0.0f        : 0.5f;
    const float K1 = tq ? 0.999904f   : 0.249976f;
    const float K3 = tq ? -0.331066f  : -0.0206916f;
    const float K5 = tq ? 0.120476f   : 0.00188244f;
    const float K7 = tq ? -0.0277200f : -0.000108281f;

    // scalar LDS index: [t*32 + bg*4 + q]; chain A at bg=2j, B at bg=2j+1 (+4 floats)
    const float* zl = (const float*)lds4 + (j * 8 + q);
    float* hp = hscan + batchA;          // all 4 quad lanes store same values

    float hA = 0.0f, cA = 0.0f;
    float hB = 0.0f, cB = 0.0f;

#define QSTEP2(ZA, ZB)                                            \
    {                                                             \
        const float uA  = fmaf(hA, sw, (ZA));                     \
        const float uB  = fmaf(hB, sw, (ZB));                     \
        const float vA  = __builtin_amdgcn_cosf(uA);              \
        const float vB  = __builtin_amdgcn_cosf(uB);              \
        const float vA2 = vA * vA;                                \
        const float vB2 = vB * vB;                                \
        const float vA4 = vA2 * vA2;                              \
        const float vB4 = vB2 * vB2;                              \
        const float phA = fmaf(vA2, K7, K5);                      \
        const float phB = fmaf(vB2, K7, K5);                      \
        const float plA = fmaf(vA2, K3, K1);                      \
        const float plB = fmaf(vB2, K3, K1);                      \
        const float gA  = fmaf(vA, fmaf(vA4, phA, plA), K0);      \
        const float gB  = fmaf(vB, fmaf(vB4, phB, plB), K0);      \
        const float fA_ = dppq<0x00>(gA);                         \
        const float fB_ = dppq<0x00>(gB);                         \
        const float iA_ = dppq<0x55>(gA);                         \
        const float iB_ = dppq<0x55>(gB);                         \
        const float gA_ = dppq<0xAA>(gA);                         \
        const float gB_ = dppq<0xAA>(gB);                         \
        const float oA_ = dppq<0xFF>(gA);                         \
        const float oB_ = dppq<0xFF>(gB);                         \
        cA = fmaf(fA_, cA, iA_ * gA_);                            \
        cB = fmaf(fB_, cB, iB_ * gB_);                            \
        hA = oA_ * tanh9(cA);                                     \
        hB = oB_ * tanh9(cB);                                     \
        hp[0] = hA;                                               \
        hp[1] = hB;                                               \
        hp += Bsz;                                                \
    }

    // 16 grouped conflict-free ds_read_b32 (A at +0, B at +4 dwords), then
    // 8 interleaved dual-chain steps.
    for (int tb = 0; tb < T; tb += 8) {
        const float* zt = zl + (size_t)tb * 32;
        const float a0 = zt[0 * 32], b0 = zt[0 * 32 + 4];
        const float a1 = zt[1 * 32], b1 = zt[1 * 32 + 4];
        const float a2 = zt[2 * 32], b2 = zt[2 * 32 + 4];
        const float a3 = zt[3 * 32], b3 = zt[3 * 32 + 4];
        const float a4 = zt[4 * 32], b4 = zt[4 * 32 + 4];
        const float a5 = zt[5 * 32], b5 = zt[5 * 32 + 4];
        const float a6 = zt[6 * 32], b6 = zt[6 * 32 + 4];
        const float a7 = zt[7 * 32], b7 = zt[7 * 32 + 4];
        QSTEP2(a0, b0); QSTEP2(a1, b1); QSTEP2(a2, b2); QSTEP2(a3, b3);
        QSTEP2(a4, b4); QSTEP2(a5, b5); QSTEP2(a6, b6); QSTEP2(a7, b7);
    }
#undef QSTEP2

    cfin[batchA]     = cA;               // 4 lanes, same value, same addr
    cfin[batchA + 1] = cB;
}

// ---------------- Kernel 3: broadcast h[t,b] across 128 hidden cols, + hx/cx tails.
__global__ __launch_bounds__(256) void bcast_kernel(
    const float* __restrict__ hscan, const float* __restrict__ cfin,
    float4* __restrict__ out)
{
    const unsigned i = blockIdx.x * 256u + threadIdx.x;  // float4 index
    const unsigned row = i >> 5;                          // output row (128 floats)
    float v;
    if (row < (unsigned)R) {
        v = hscan[row];
    } else {
        const unsigned r2 = row - (unsigned)R;
        v = (r2 < (unsigned)Bsz) ? hscan[(T - 1) * Bsz + r2] : cfin[r2 - (unsigned)Bsz];
    }
    out[i] = make_float4(v, v, v, v);
}

extern "C" void kernel_launch(void* const* d_in, const int* in_sizes, int n_in,
                              void* d_out, int out_size, void* d_ws, size_t ws_size,
                              hipStream_t stream)
{
    const float* x  = (const float*)d_in[0];
    const float* Wf = (const float*)d_in[1];
    const float* bf = (const float*)d_in[2];
    const float* tf = (const float*)d_in[3];
    const float* Wi = (const float*)d_in[4];
    const float* bi = (const float*)d_in[5];
    const float* ti = (const float*)d_in[6];
    const float* Wu = (const float*)d_in[7];
    const float* bu = (const float*)d_in[8];
    const float* tu = (const float*)d_in[9];
    const float* Wo = (const float*)d_in[10];
    const float* bo = (const float*)d_in[11];
    const float* to_ = (const float*)d_in[12];

    float* ws    = (float*)d_ws;
    float4* xz   = (float4*)ws;       // R float4s  (4*R floats)
    float* hscan = ws + 4 * R;        // R floats
    float* cfin  = ws + 5 * R;        // Bsz floats

    xz_kernel<<<2048, 256, 0, stream>>>(x, Wf, bf, tf, Wi, bi, ti, Wu, bu, tu, Wo, bo, to_, xz);
    scan_kernel<<<SCAN_BLOCKS, 256, 0, stream>>>(xz, Wf, Wi, Wu, Wo, hscan, cfin);

    const int total_f4 = (R + 2 * Bsz) * 32;              // 4,210,688
    bcast_kernel<<<total_f4 / 256, 256, 0, stream>>>(hscan, cfin, (float4*)d_out);
}

// Round 14
// 73.670 us; speedup vs baseline: 5.8936x; 1.2696x over previous
//
#include <hip/hip_runtime.h>
#include <hip/hip_bf16.h>

// QLSTM: T=512, B=256, D_IN=128, D_H=128.
// Gates are per-batch SCALARS broadcast over hidden dim => h,c uniform across
// hidden dim. comb@W[0] = x@W[0][:128] + h*sum(W[0][128:]).
// R13 post-mortem: scan wall = 512 x single-step serial latency; extra chains/
// lanes/waves don't help. R14 = R11 + step trims: h stored to LDS (no global
// store/pointer bump in loop; bulk flush at end by all 4 waves), deg-5 gate
// polys (sig err 1.1e-4, tanh err 1.5e-3), 19-instr QSTEP.

constexpr int T = 512;
constexpr int Bsz = 256;
constexpr int R = T * Bsz;          // 131072 rows
constexpr float INV2PI = 0.15915494309189535f;

// ---------------- Kernel 1: xz[row] = float4(zf,zi,zu,zo)/(2pi), row = t*B+b
__global__ __launch_bounds__(256) void xz_kernel(
    const float* __restrict__ x,
    const float* __restrict__ Wf, const float* __restrict__ bf, const float* __restrict__ tf,
    const float* __restrict__ Wi, const float* __restrict__ bi, const float* __restrict__ ti,
    const float* __restrict__ Wu, const float* __restrict__ bu, const float* __restrict__ tu,
    const float* __restrict__ Wo, const float* __restrict__ bo, const float* __restrict__ to_,
    float4* __restrict__ xz)
{
    const int wglobal = blockIdx.x * 4 + (threadIdx.x >> 6);   // 0..8191
    const int lane = threadIdx.x & 63;
    const int hl = lane & 31;            // lane within half-wave
    const int half = lane >> 5;          // which row of the pair

    const float4 wfv = ((const float4*)Wf)[hl];
    const float4 wiv = ((const float4*)Wi)[hl];
    const float4 wuv = ((const float4*)Wu)[hl];
    const float4 wov = ((const float4*)Wo)[hl];

    const float cf = bf[0] + tf[0];
    const float ci = bi[0] + ti[0];
    const float cu = bu[0] + tu[0];
    const float co = bo[0] + to_[0];

    for (int it = 0; it < 8; ++it) {
        const int row = (it * 8192 + wglobal) * 2 + half;
        const float4 xv = *(const float4*)(x + (size_t)row * 128 + hl * 4);

        float pf = xv.x * wfv.x + xv.y * wfv.y + xv.z * wfv.z + xv.w * wfv.w;
        float pi = xv.x * wiv.x + xv.y * wiv.y + xv.z * wiv.z + xv.w * wiv.w;
        float pu = xv.x * wuv.x + xv.y * wuv.y + xv.z * wuv.z + xv.w * wuv.w;
        float po = xv.x * wov.x + xv.y * wov.y + xv.z * wov.z + xv.w * wov.w;

#pragma unroll
        for (int off = 16; off; off >>= 1) {
            pf += __shfl_xor(pf, off, 64);
            pi += __shfl_xor(pi, off, 64);
            pu += __shfl_xor(pu, off, 64);
            po += __shfl_xor(po, off, 64);
        }
        if (hl == 0) {
            xz[row] = make_float4((pf + cf) * INV2PI, (pi + ci) * INV2PI,
                                  (pu + cu) * INV2PI, (po + co) * INV2PI);
        }
    }
}

// ---------------- Kernel 2: scan, LDS z-in + LDS h-out, 4 lanes/batch.
// tanh(c), |c|<=2.07 (provable bound): odd deg-9 polynomial (no rcp),
// err ~1e-3 typ, <=5e-3 near endpoint. Estrin: path c->y->y2->fma->mul = 16cy.
__device__ __forceinline__ float tanh9(float c) {
    const float y  = c * c;
    const float y2 = y * y;
    const float lo  = fmaf(y, -0.321470f, 0.999168f);
    const float hi  = fmaf(y, 0.0016407f, -0.0199491f);
    const float mid = fmaf(y, hi, 0.101498f);
    return c * fmaf(y2, mid, lo);
}

template<int CTRL>
__device__ __forceinline__ float dppq(float x) {
    return __builtin_bit_cast(float,
        __builtin_amdgcn_mov_dpp(__builtin_bit_cast(int, x), CTRL, 0xF, 0xF, true));
}

__device__ __forceinline__ float wsum(const float* __restrict__ W, int lane) {
    float s = W[128 + lane] + W[192 + lane];
#pragma unroll
    for (int off = 32; off; off >>= 1) s += __shfl_xor(s, off, 64);
    return s;  // butterfly: all lanes hold the sum
}

constexpr int BPB = 8;                   // batches per scan block
constexpr int SCAN_BLOCKS = Bsz / BPB;   // 32

__global__ __launch_bounds__(256, 1) void scan_kernel(
    const float4* __restrict__ xz,
    const float* __restrict__ Wf, const float* __restrict__ Wi,
    const float* __restrict__ Wu, const float* __restrict__ Wo,
    float* __restrict__ hscan, float* __restrict__ cfin)
{
    __shared__ float4 zb4[T * BPB];      // 64 KB z slice, [t][bg] float4
    __shared__ float  hb[T * 32];        // 64 KB h out, [t*32 + lane] (quad-replicated)
    const int tid = threadIdx.x;
    const int bb = blockIdx.x * BPB;

    // ---- stage the entire z slice: 256 threads x 16 float4 loads
#pragma unroll
    for (int k = 0; k < T * BPB / 256; ++k) {      // 16 iterations
        const int j = k * 256 + tid;               // 0..4095
        zb4[j] = xz[(j >> 3) * Bsz + bb + (j & 7)];
    }

    // ---- per-gate hidden-weight sums (wave-wide butterfly, every wave)
    const int l = tid & 63;
    const float swf = wsum(Wf, l) * INV2PI;
    const float swi = wsum(Wi, l) * INV2PI;
    const float swu = wsum(Wu, l) * INV2PI;
    const float swo = wsum(Wo, l) * INV2PI;

    __syncthreads();

    if (tid < BPB * 4) {                 // lanes 0..31 of wave 0 scan
        const int q = tid & 3;           // gate: 0=f 1=i 2=g(tanh) 3=o
        const int batch = bb + (tid >> 2);

        const float sw = (q == 0) ? swf : (q == 1) ? swi : (q == 2) ? swu : swo;

        // deg-5 odd gate polynomial in v = cos(u):
        //   tanh lane (q==2): tanh(v) (err ~1.5e-3);
        //   sigmoid lanes: 0.5 + 0.5*tanh(v/2) folded (err ~1.1e-4).
        const bool tq = (q == 2);
        const float K0 = tq ? 0.0f       : 0.5f;
        const float K1 = tq ? 0.999318f  : 0.249976f;
        const float K3 = tq ? -0.319476f : -0.0206916f;
        const float K5 = tq ? 0.08315f   : 0.00188244f;

        const float* zl = (const float*)zb4 + tid;  // scalar [t*32 + bg*4 + q]
        float* hw = hb + tid;                       // h slot [t*32 + tid]

        float h = 0.0f, c = 0.0f;

#define QSTEP(Z, S)                                               \
    {                                                             \
        const float u  = fmaf(h, sw, (Z));                        \
        const float v  = __builtin_amdgcn_cosf(u);                \
        const float v2 = v * v;                                   \
        const float t1 = fmaf(v2, K5, K3);                        \
        const float p  = fmaf(v2, t1, K1);                        \
        const float gown = fmaf(v, p, K0);                        \
        const float f = dppq<0x00>(gown);                         \
        const float i = dppq<0x55>(gown);                         \
        const float g = dppq<0xAA>(gown);                         \
        const float o = dppq<0xFF>(gown);                         \
        c = fmaf(f, c, i * g);                                    \
        h = o * tanh9(c);                                         \
        hw[(S) * 32] = h;                                         \
    }

        // 8 grouped conflict-free ds_read_b32 (bank = lane), then 8 serial
        // steps; h goes to LDS via ds_write + imm offset (no pointer bump).
        for (int tb = 0; tb < T; tb += 8) {
            const float* zt = zl + (size_t)tb * 32;
            float* ht = hw + (size_t)tb * 32;
            const float y0 = zt[0 * 32];
            const float y1 = zt[1 * 32];
            const float y2 = zt[2 * 32];
            const float y3 = zt[3 * 32];
            const float y4 = zt[4 * 32];
            const float y5 = zt[5 * 32];
            const float y6 = zt[6 * 32];
            const float y7 = zt[7 * 32];
#define HSTEP(Y, S) { const float u=fmaf(h,sw,(Y)); const float v=__builtin_amdgcn_cosf(u); \
        const float v2=v*v; const float t1=fmaf(v2,K5,K3); const float p=fmaf(v2,t1,K1);   \
        const float gown=fmaf(v,p,K0);                                                      \
        const float f=dppq<0x00>(gown); const float i=dppq<0x55>(gown);                     \
        const float g=dppq<0xAA>(gown); const float o=dppq<0xFF>(gown);                     \
        c=fmaf(f,c,i*g); h=o*tanh9(c); ht[(S)*32]=h; }
            HSTEP(y0, 0); HSTEP(y1, 1); HSTEP(y2, 2); HSTEP(y3, 3);
            HSTEP(y4, 4); HSTEP(y5, 5); HSTEP(y6, 6); HSTEP(y7, 7);
#undef HSTEP
        }
#undef QSTEP

        cfin[batch] = c;                 // 4 quad lanes, same value, same addr
    }

    __syncthreads();                     // waves 1-3 parked here during scan

    // ---- bulk flush LDS h -> hscan (all 256 threads, one-time)
    for (int j = tid; j < T * BPB; j += 256) {     // 4096 values
        const int t = j >> 3, bg = j & 7;
        hscan[t * Bsz + bb + bg] = hb[t * 32 + bg * 4];
    }
}

// ---------------- Kernel 3: broadcast h[t,b] across 128 hidden cols, + hx/cx tails.
__global__ __launch_bounds__(256) void bcast_kernel(
    const float* __restrict__ hscan, const float* __restrict__ cfin,
    float4* __restrict__ out)
{
    const unsigned i = blockIdx.x * 256u + threadIdx.x;  // float4 index
    const unsigned row = i >> 5;                          // output row (128 floats)
    float v;
    if (row < (unsigned)R) {
        v = hscan[row];
    } else {
        const unsigned r2 = row - (unsigned)R;
        v = (r2 < (unsigned)Bsz) ? hscan[(T - 1) * Bsz + r2] : cfin[r2 - (unsigned)Bsz];
    }
    out[i] = make_float4(v, v, v, v);
}

extern "C" void kernel_launch(void* const* d_in, const int* in_sizes, int n_in,
                              void* d_out, int out_size, void* d_ws, size_t ws_size,
                              hipStream_t stream)
{
    const float* x  = (const float*)d_in[0];
    const float* Wf = (const float*)d_in[1];
    const float* bf = (const float*)d_in[2];
    const float* tf = (const float*)d_in[3];
    const float* Wi = (const float*)d_in[4];
    const float* bi = (const float*)d_in[5];
    const float* ti = (const float*)d_in[6];
    const float* Wu = (const float*)d_in[7];
    const float* bu = (const float*)d_in[8];
    const float* tu = (const float*)d_in[9];
    const float* Wo = (const float*)d_in[10];
    const float* bo = (const float*)d_in[11];
    const float* to_ = (const float*)d_in[12];

    float* ws    = (float*)d_ws;
    float4* xz   = (float4*)ws;       // R float4s  (4*R floats)
    float* hscan = ws + 4 * R;        // R floats
    float* cfin  = ws + 5 * R;        // Bsz floats

    xz_kernel<<<2048, 256, 0, stream>>>(x, Wf, bf, tf, Wi, bi, ti, Wu, bu, tu, Wo, bo, to_, xz);
    scan_kernel<<<SCAN_BLOCKS, 256, 0, stream>>>(xz, Wf, Wi, Wu, Wo, hscan, cfin);

    const int total_f4 = (R + 2 * Bsz) * 32;              // 4,210,688
    bcast_kernel<<<total_f4 / 256, 256, 0, stream>>>(hscan, cfin, (float4*)d_out);
}

// Round 15
// 71.933 us; speedup vs baseline: 6.0359x; 1.0241x over previous
//
#include <hip/hip_runtime.h>
#include <hip/hip_bf16.h>

// QLSTM: T=512, B=256, D_IN=128, D_H=128.
// Gates are per-batch SCALARS broadcast over hidden dim => h,c uniform across
// hidden dim. comb@W[0] = x@W[0][:128] + h*sum(W[0][128:]).
// R14 post-mortem: scan wall = 512 x (issue 75 + VALU-chain ~55 + ds first-use
// ~15 + trans/DPP latency). R15: tc/os carry (chain -1 op), group-ahead LDS
// prefetch (hide the 120cy ds_read first-use wait), nontemporal bcast stores.

constexpr int T = 512;
constexpr int Bsz = 256;
constexpr int R = T * Bsz;          // 131072 rows
constexpr float INV2PI = 0.15915494309189535f;

typedef float f4v __attribute__((ext_vector_type(4)));

// ---------------- Kernel 1: xz[row] = float4(zf,zi,zu,zo)/(2pi), row = t*B+b
__global__ __launch_bounds__(256) void xz_kernel(
    const float* __restrict__ x,
    const float* __restrict__ Wf, const float* __restrict__ bf, const float* __restrict__ tf,
    const float* __restrict__ Wi, const float* __restrict__ bi, const float* __restrict__ ti,
    const float* __restrict__ Wu, const float* __restrict__ bu, const float* __restrict__ tu,
    const float* __restrict__ Wo, const float* __restrict__ bo, const float* __restrict__ to_,
    float4* __restrict__ xz)
{
    const int wglobal = blockIdx.x * 4 + (threadIdx.x >> 6);   // 0..8191
    const int lane = threadIdx.x & 63;
    const int hl = lane & 31;            // lane within half-wave
    const int half = lane >> 5;          // which row of the pair

    const float4 wfv = ((const float4*)Wf)[hl];
    const float4 wiv = ((const float4*)Wi)[hl];
    const float4 wuv = ((const float4*)Wu)[hl];
    const float4 wov = ((const float4*)Wo)[hl];

    const float cf = bf[0] + tf[0];
    const float ci = bi[0] + ti[0];
    const float cu = bu[0] + tu[0];
    const float co = bo[0] + to_[0];

    for (int it = 0; it < 8; ++it) {
        const int row = (it * 8192 + wglobal) * 2 + half;
        const float4 xv = *(const float4*)(x + (size_t)row * 128 + hl * 4);

        float pf = xv.x * wfv.x + xv.y * wfv.y + xv.z * wfv.z + xv.w * wfv.w;
        float pi = xv.x * wiv.x + xv.y * wiv.y + xv.z * wiv.z + xv.w * wiv.w;
        float pu = xv.x * wuv.x + xv.y * wuv.y + xv.z * wuv.z + xv.w * wuv.w;
        float po = xv.x * wov.x + xv.y * wov.y + xv.z * wov.z + xv.w * wov.w;

#pragma unroll
        for (int off = 16; off; off >>= 1) {
            pf += __shfl_xor(pf, off, 64);
            pi += __shfl_xor(pi, off, 64);
            pu += __shfl_xor(pu, off, 64);
            po += __shfl_xor(po, off, 64);
        }
        if (hl == 0) {
            xz[row] = make_float4((pf + cf) * INV2PI, (pi + ci) * INV2PI,
                                  (pu + cu) * INV2PI, (po + co) * INV2PI);
        }
    }
}

// ---------------- Kernel 2: scan, LDS z-in + LDS h-out, 4 lanes/batch.
// tanh(c), |c|<=2.07 (provable bound): odd deg-9 polynomial (no rcp),
// err ~1e-3 typ, <=5e-3 near endpoint.
__device__ __forceinline__ float tanh9(float c) {
    const float y  = c * c;
    const float y2 = y * y;
    const float lo  = fmaf(y, -0.321470f, 0.999168f);
    const float hi  = fmaf(y, 0.0016407f, -0.0199491f);
    const float mid = fmaf(y, hi, 0.101498f);
    return c * fmaf(y2, mid, lo);
}

template<int CTRL>
__device__ __forceinline__ float dppq(float x) {
    return __builtin_bit_cast(float,
        __builtin_amdgcn_mov_dpp(__builtin_bit_cast(int, x), CTRL, 0xF, 0xF, true));
}

__device__ __forceinline__ float wsum(const float* __restrict__ W, int lane) {
    float s = W[128 + lane] + W[192 + lane];
#pragma unroll
    for (int off = 32; off; off >>= 1) s += __shfl_xor(s, off, 64);
    return s;  // butterfly: all lanes hold the sum
}

constexpr int BPB = 8;                   // batches per scan block
constexpr int SCAN_BLOCKS = Bsz / BPB;   // 32

__global__ __launch_bounds__(256, 1) void scan_kernel(
    const float4* __restrict__ xz,
    const float* __restrict__ Wf, const float* __restrict__ Wi,
    const float* __restrict__ Wu, const float* __restrict__ Wo,
    float* __restrict__ hscan, float* __restrict__ cfin)
{
    __shared__ float4 zb4[T * BPB];      // 64 KB z slice, [t][bg] float4
    __shared__ float  hb[T * 32];        // 64 KB h out, [t*32 + lane] (quad-replicated)
    const int tid = threadIdx.x;
    const int bb = blockIdx.x * BPB;

    // ---- stage the entire z slice: 256 threads x 16 float4 loads
#pragma unroll
    for (int k = 0; k < T * BPB / 256; ++k) {      // 16 iterations
        const int j = k * 256 + tid;               // 0..4095
        zb4[j] = xz[(j >> 3) * Bsz + bb + (j & 7)];
    }

    // ---- per-gate hidden-weight sums (wave-wide butterfly, every wave)
    const int l = tid & 63;
    const float swf = wsum(Wf, l) * INV2PI;
    const float swi = wsum(Wi, l) * INV2PI;
    const float swu = wsum(Wu, l) * INV2PI;
    const float swo = wsum(Wo, l) * INV2PI;

    __syncthreads();

    if (tid < BPB * 4) {                 // lanes 0..31 of wave 0 scan
        const int q = tid & 3;           // gate: 0=f 1=i 2=g(tanh) 3=o
        const int batch = bb + (tid >> 2);

        const float sw = (q == 0) ? swf : (q == 1) ? swi : (q == 2) ? swu : swo;

        // deg-5 odd gate polynomial in v = cos(u):
        //   tanh lane (q==2): tanh(v) (err ~1.5e-3);
        //   sigmoid lanes: 0.5 + 0.5*tanh(v/2) folded (err ~1.1e-4).
        const bool tq = (q == 2);
        const float K0 = tq ? 0.0f       : 0.5f;
        const float K1 = tq ? 0.999318f  : 0.249976f;
        const float K3 = tq ? -0.319476f : -0.0206916f;
        const float K5 = tq ? 0.08315f   : 0.00188244f;

        const float* zl = (const float*)zb4 + tid;  // scalar [t*32 + bg*4 + q]
        float* hw = hb + tid;                       // h slot [t*32 + tid]

        // carried state: c, tc = tanh9(c), os = o*sw  (h = o*tc off-path)
        float c = 0.0f, tc = 0.0f, os = 0.0f;

// serial cycle: u -> cos -> v2 -> t1 -> p -> gown -> dpp -> ig -> cfma ->
// tanh9 -> u(next).  os = o*sw and h = o*tc run parallel to tanh9.
#define HSTEP(Y, HT, S)                                            \
    {                                                              \
        const float u  = fmaf(tc, os, (Y));                        \
        const float v  = __builtin_amdgcn_cosf(u);                 \
        const float v2 = v * v;                                    \
        const float t1 = fmaf(v2, K5, K3);                         \
        const float p  = fmaf(v2, t1, K1);                         \
        const float gown = fmaf(v, p, K0);                         \
        const float f = dppq<0x00>(gown);                          \
        const float i = dppq<0x55>(gown);                          \
        const float g = dppq<0xAA>(gown);                          \
        const float o = dppq<0xFF>(gown);                          \
        c  = fmaf(f, c, i * g);                                    \
        tc = tanh9(c);                                             \
        os = o * sw;                                               \
        (HT)[(S) * 32] = o * tc;                                   \
    }

        // group-ahead prefetch: next 8-step z-group is read into named regs
        // BEFORE the current group is consumed -> ds_read first-use wait
        // (~120cy) covered by ~8 steps of compute.
        float p0 = zl[0 * 32], p1 = zl[1 * 32], p2 = zl[2 * 32], p3 = zl[3 * 32];
        float p4 = zl[4 * 32], p5 = zl[5 * 32], p6 = zl[6 * 32], p7 = zl[7 * 32];

        for (int tb = 0; tb < T - 8; tb += 8) {
            const float* zn = zl + (size_t)(tb + 8) * 32;
            const float n0 = zn[0 * 32];
            const float n1 = zn[1 * 32];
            const float n2 = zn[2 * 32];
            const float n3 = zn[3 * 32];
            const float n4 = zn[4 * 32];
            const float n5 = zn[5 * 32];
            const float n6 = zn[6 * 32];
            const float n7 = zn[7 * 32];
            float* ht = hw + (size_t)tb * 32;
            HSTEP(p0, ht, 0); HSTEP(p1, ht, 1); HSTEP(p2, ht, 2); HSTEP(p3, ht, 3);
            HSTEP(p4, ht, 4); HSTEP(p5, ht, 5); HSTEP(p6, ht, 6); HSTEP(p7, ht, 7);
            p0 = n0; p1 = n1; p2 = n2; p3 = n3;
            p4 = n4; p5 = n5; p6 = n6; p7 = n7;
        }
        {   // epilogue group
            float* ht = hw + (size_t)(T - 8) * 32;
            HSTEP(p0, ht, 0); HSTEP(p1, ht, 1); HSTEP(p2, ht, 2); HSTEP(p3, ht, 3);
            HSTEP(p4, ht, 4); HSTEP(p5, ht, 5); HSTEP(p6, ht, 6); HSTEP(p7, ht, 7);
        }
#undef HSTEP

        cfin[batch] = c;                 // 4 quad lanes, same value, same addr
    }

    __syncthreads();                     // waves 1-3 parked here during scan

    // ---- bulk flush LDS h -> hscan (all 256 threads, one-time)
    for (int j = tid; j < T * BPB; j += 256) {     // 4096 values
        const int t = j >> 3, bg = j & 7;
        hscan[t * Bsz + bb + bg] = hb[t * 32 + bg * 4];
    }
}

// ---------------- Kernel 3: broadcast h[t,b] across 128 hidden cols, + hx/cx tails.
__global__ __launch_bounds__(256) void bcast_kernel(
    const float* __restrict__ hscan, const float* __restrict__ cfin,
    float4* __restrict__ out)
{
    const unsigned i = blockIdx.x * 256u + threadIdx.x;  // float4 index
    const unsigned row = i >> 5;                          // output row (128 floats)
    float v;
    if (row < (unsigned)R) {
        v = hscan[row];
    } else {
        const unsigned r2 = row - (unsigned)R;
        v = (r2 < (unsigned)Bsz) ? hscan[(T - 1) * Bsz + r2] : cfin[r2 - (unsigned)Bsz];
    }
    const f4v val = {v, v, v, v};
    __builtin_nontemporal_store(val, (f4v*)&out[i]);     // write-only stream
}

extern "C" void kernel_launch(void* const* d_in, const int* in_sizes, int n_in,
                              void* d_out, int out_size, void* d_ws, size_t ws_size,
                              hipStream_t stream)
{
    const float* x  = (const float*)d_in[0];
    const float* Wf = (const float*)d_in[1];
    const float* bf = (const float*)d_in[2];
    const float* tf = (const float*)d_in[3];
    const float* Wi = (const float*)d_in[4];
    const float* bi = (const float*)d_in[5];
    const float* ti = (const float*)d_in[6];
    const float* Wu = (const float*)d_in[7];
    const float* bu = (const float*)d_in[8];
    const float* tu = (const float*)d_in[9];
    const float* Wo = (const float*)d_in[10];
    const float* bo = (const float*)d_in[11];
    const float* to_ = (const float*)d_in[12];

    float* ws    = (float*)d_ws;
    float4* xz   = (float4*)ws;       // R float4s  (4*R floats)
    float* hscan = ws + 4 * R;        // R floats
    float* cfin  = ws + 5 * R;        // Bsz floats

    xz_kernel<<<2048, 256, 0, stream>>>(x, Wf, bf, tf, Wi, bi, ti, Wu, bu, tu, Wo, bo, to_, xz);
    scan_kernel<<<SCAN_BLOCKS, 256, 0, stream>>>(xz, Wf, Wi, Wu, Wo, hscan, cfin);

    const int total_f4 = (R + 2 * Bsz) * 32;              // 4,210,688
    bcast_kernel<<<total_f4 / 256, 256, 0, stream>>>(hscan, cfin, (float4*)d_out);
}